// Round 6
// baseline (83.112 us; speedup 1.0000x reference)
//
#include <hip/hip_runtime.h>
#include <hip/hip_bf16.h>
#include <math.h>

typedef float f4 __attribute__((ext_vector_type(4)));
typedef float f32x4 __attribute__((ext_vector_type(4)));
typedef short bf16x8 __attribute__((ext_vector_type(8)));
typedef unsigned int u32x4 __attribute__((ext_vector_type(4)));

#define D      2048
#define NE     64
#define TOKB   16               // tokens per block
#define KSPLIT 4                // waves per block (k-split in-block)
#define KRNG   (D / KSPLIT)     // 512 k per wave
#define KCH    32               // k per chunk = one MFMA K-slab
#define NCH    (KRNG / KCH)     // 16 chunks
#define CSTR   68               // f32 stride of reduction rows

__device__ __forceinline__ unsigned short bf16rne(float f) {
    unsigned int u = __builtin_bit_cast(unsigned int, f);
    u += 0x7fffu + ((u >> 16) & 1u);
    return (unsigned short)(u >> 16);
}
__device__ __forceinline__ float bf2f(unsigned short h) {
    unsigned int u = (unsigned int)h << 16;
    return __builtin_bit_cast(float, u);
}

// ---- kernel 0: W -> (Wh, Wl) bf16 split, [e][k] layout kept ----
__global__ __launch_bounds__(256)
void wprep(const float* __restrict__ W,
           unsigned short* __restrict__ Wh,
           unsigned short* __restrict__ Wl)
{
    const int i = blockIdx.x * 256 + threadIdx.x;
    const float w = W[i];
    const unsigned short h = bf16rne(w);
    Wh[i] = h;
    Wl[i] = bf16rne(w - bf2f(h));
}

// hi/lo split of a float pair via HW v_cvt_pk_bf16_f32 (~6 VALU / 2 elems).
// NOTE: __builtin_memcpy (not bit_cast) — __hip_bfloat162 is not trivially
// copyable under hipcc, memcpy is byte-legal and folds to a register alias.
#define CVTPAIR(F0, F1, HOUT, LOUT) {                                        \
    __hip_bfloat162 hp_ = __float22bfloat162_rn(make_float2((F0), (F1)));    \
    unsigned hu_; __builtin_memcpy(&hu_, &hp_, 4);                           \
    const float h0_ = __builtin_bit_cast(float, hu_ << 16);                  \
    const float h1_ = __builtin_bit_cast(float, hu_ & 0xffff0000u);          \
    __hip_bfloat162 lp_ = __float22bfloat162_rn(                             \
        make_float2((F0) - h0_, (F1) - h1_));                                \
    unsigned lu_; __builtin_memcpy(&lu_, &lp_, 4);                           \
    HOUT = hu_;                                                              \
    LOUT = lu_;                                                              \
}

// ---- kernel 1: fused logits (3-term bf16 split-MFMA) + reduce + top2 ----
// No LDS in main loop: A-frag loaded per-lane direct from global
// (lane l: row tok0+(l&15), k-slice (l>>4)*8 — L1 merges the 16B segments),
// depth-2 register prefetch; B-frags from L2-resident Wh/Wl.
__global__ __launch_bounds__(256)
void moe_fused(const float* __restrict__ x,
               const unsigned short* __restrict__ Wh,
               const unsigned short* __restrict__ Wl,
               float* __restrict__ out, int ntok)
{
    __shared__ float cred[KSPLIT][TOKB * CSTR];   // epilogue only (17.4 KB)

    const int t    = threadIdx.x;
    const int w    = t >> 6;            // wave id = k-split id
    const int l    = t & 63;
    const int tok0 = blockIdx.x * TOKB;
    const int k0   = w * KRNG;

    const int ar  = l & 15;             // A row (token) / B col (expert)
    const int akb = (l >> 4) * 8;       // k-slice within 32-k chunk

    const float*          xa  = x  + (size_t)(tok0 + ar) * D + k0 + akb;
    const unsigned short* whb = Wh + (size_t)ar * D + k0 + akb;
    const unsigned short* wlb = Wl + (size_t)ar * D + k0 + akb;

    const f32x4 zz = {0.f, 0.f, 0.f, 0.f};
    f32x4 acc[4] = {zz, zz, zz, zz};

    // depth-2 prefetch registers (named: parity-static, rule #20)
    f4 rA0 = *(const f4*)(xa);
    f4 rA1 = *(const f4*)(xa + 4);
    f4 rB0 = *(const f4*)(xa + KCH);
    f4 rB1 = *(const f4*)(xa + KCH + 4);

#define BODY(RA0, RA1, ch) {                                                 \
    /* B frags for this chunk (L2-resident, coalesced 64B/expert) */         \
    bf16x8 bh[4], bl[4];                                                     \
    const size_t kk_ = (size_t)(ch) * KCH;                                   \
    _Pragma("unroll")                                                        \
    for (int et = 0; et < 4; ++et) {                                         \
        bh[et] = *(const bf16x8*)(whb + (size_t)et * 16 * D + kk_);          \
        bl[et] = *(const bf16x8*)(wlb + (size_t)et * 16 * D + kk_);          \
    }                                                                        \
    /* convert A (waits on RA's loads, issued 2 chunks ago) */               \
    unsigned hu0_, hu1_, hu2_, hu3_, lu0_, lu1_, lu2_, lu3_;                 \
    CVTPAIR(RA0.x, RA0.y, hu0_, lu0_);                                       \
    CVTPAIR(RA0.z, RA0.w, hu1_, lu1_);                                       \
    CVTPAIR(RA1.x, RA1.y, hu2_, lu2_);                                       \
    CVTPAIR(RA1.z, RA1.w, hu3_, lu3_);                                       \
    const u32x4 hv_ = {hu0_, hu1_, hu2_, hu3_};                              \
    const u32x4 lv_ = {lu0_, lu1_, lu2_, lu3_};                              \
    const bf16x8 ah = __builtin_bit_cast(bf16x8, hv_);                       \
    const bf16x8 al = __builtin_bit_cast(bf16x8, lv_);                       \
    /* refill RA with chunk ch+2 (stays in flight across next BODY) */       \
    if ((ch) + 2 < NCH) {                                                    \
        RA0 = *(const f4*)(xa + ((ch) + 2) * KCH);                           \
        RA1 = *(const f4*)(xa + ((ch) + 2) * KCH + 4);                       \
    }                                                                        \
    /* 3-term split product: xh*wh + xh*wl + xl*wh */                        \
    _Pragma("unroll")                                                        \
    for (int et = 0; et < 4; ++et) {                                         \
        acc[et] = __builtin_amdgcn_mfma_f32_16x16x32_bf16(ah, bh[et], acc[et], 0, 0, 0); \
        acc[et] = __builtin_amdgcn_mfma_f32_16x16x32_bf16(ah, bl[et], acc[et], 0, 0, 0); \
        acc[et] = __builtin_amdgcn_mfma_f32_16x16x32_bf16(al, bh[et], acc[et], 0, 0, 0); \
    }                                                                        \
}

    for (int ch = 0; ch < NCH; ch += 2) {
        BODY(rA0, rA1, ch);
        BODY(rB0, rB1, ch + 1);
    }
#undef BODY

    // ---- per-wave partials -> LDS ----
    // C/D layout (verified r4): token = (l>>4)*4 + r, expert = et*16 + (l&15)
#pragma unroll
    for (int et = 0; et < 4; ++et)
#pragma unroll
        for (int r = 0; r < 4; ++r) {
            const int tokl = (l >> 4) * 4 + r;
            cred[w][tokl * CSTR + et * 16 + (l & 15)] = acc[et][r];
        }
    __syncthreads();

    // ---- reduce 4 k-splits + top-2 + softmax (128 active threads) ----
    if (t < TOKB * 8) {
        const int tokl = t >> 3;        // 0..15
        const int eg   = t & 7;         // expert octet
        f4 s0 = {0.f,0.f,0.f,0.f}, s1 = {0.f,0.f,0.f,0.f};
#pragma unroll
        for (int ww = 0; ww < KSPLIT; ++ww) {
            const float* cw = &cred[ww][tokl * CSTR + eg * 8];
            s0 += *(const f4*)cw;
            s1 += *(const f4*)(cw + 4);
        }
        const float vv[8] = {s0.x, s0.y, s0.z, s0.w, s1.x, s1.y, s1.z, s1.w};
        float m1 = -INFINITY, m2 = -INFINITY;
        int i1 = 0, i2 = 0;
#pragma unroll
        for (int j = 0; j < 8; ++j) {   // ids ascending: strict > = lowest-index tie-break
            const float v = vv[j];
            const int id = eg * 8 + j;
            if (v > m1)      { m2 = m1; i2 = i1; m1 = v; i1 = id; }
            else if (v > m2) { m2 = v;  i2 = id; }
        }
#pragma unroll
        for (int m = 1; m < 8; m <<= 1) {
            const float om1 = __shfl_xor(m1, m);
            const int   oi1 = __shfl_xor(i1, m);
            const float om2 = __shfl_xor(m2, m);
            const int   oi2 = __shfl_xor(i2, m);
            const bool b1 = (om1 > m1) || (om1 == m1 && oi1 < i1);
            const float c2v = b1 ? m1 : om1;  const int c2i = b1 ? i1 : oi1;
            const float c3v = b1 ? om2 : m2;  const int c3i = b1 ? oi2 : i2;
            if (b1) { m1 = om1; i1 = oi1; }
            const bool b2 = (c3v > c2v) || (c3v == c2v && c3i < c2i);
            m2 = b2 ? c3v : c2v;  i2 = b2 ? c3i : c2i;
        }
        if (eg == 0) {
            const int tok = tok0 + tokl;
            out[(size_t)tok * 2 + 0] = (float)i1;
            out[(size_t)tok * 2 + 1] = (float)i2;
            const float p1 = 1.0f / (1.0f + expf(m2 - m1));   // stable: m2 <= m1
            float* vals = out + (size_t)ntok * 2;
            vals[(size_t)tok * 2 + 0] = p1;
            vals[(size_t)tok * 2 + 1] = 1.0f - p1;
        }
    }
}

extern "C" void kernel_launch(void* const* d_in, const int* in_sizes, int n_in,
                              void* d_out, int out_size, void* d_ws, size_t ws_size,
                              hipStream_t stream)
{
    const float* x = (const float*)d_in[0];
    const float* W = (const float*)d_in[1];
    float* out = (float*)d_out;
    unsigned short* Wh = (unsigned short*)d_ws;
    unsigned short* Wl = Wh + (size_t)NE * D;

    const int ntok = in_sizes[0] / D;                 // 16384
    wprep<<<(NE * D) / 256, 256, 0, stream>>>(W, Wh, Wl);
    moe_fused<<<ntok / TOKB, 256, 0, stream>>>(x, Wh, Wl, out, ntok);
}

// Round 7
// 48.479 us; speedup vs baseline: 1.7144x; 1.7144x over previous
//
#include <hip/hip_runtime.h>
#include <hip/hip_bf16.h>
#include <math.h>

typedef float f4 __attribute__((ext_vector_type(4)));
typedef float f32x4 __attribute__((ext_vector_type(4)));
typedef short bf16x8 __attribute__((ext_vector_type(8)));

#define D      2048
#define NE     64
#define TOKB   32               // tokens per block
#define KSPLIT 8                // waves per block, k-split in-block
#define KRNG   (D / KSPLIT)     // 256 k per wave
#define KCH    32               // k per chunk
#define NCH    (KRNG / KCH)     // 8 chunks
#define LROW   40               // ushorts per staged row (64B data + 16B pad)
#define SLAB   10240            // bytes per wave LDS slab
#define CSTR   68               // f32 stride of reduction rows

__device__ __forceinline__ unsigned short bf16rne(float f) {
    unsigned int u = __builtin_bit_cast(unsigned int, f);
    u += 0x7fffu + ((u >> 16) & 1u);
    return (unsigned short)(u >> 16);
}
__device__ __forceinline__ float bf2f(unsigned short h) {
    unsigned int u = (unsigned int)h << 16;
    return __builtin_bit_cast(float, u);
}

// ---- kernel 0: W -> (Wh, Wl) bf16 split, [e][k] layout kept ----
__global__ __launch_bounds__(256)
void wprep(const float* __restrict__ W,
           unsigned short* __restrict__ Wh,
           unsigned short* __restrict__ Wl)
{
    const int i = blockIdx.x * 256 + threadIdx.x;
    const float w = W[i];
    const unsigned short h = bf16rne(w);
    Wh[i] = h;
    Wl[i] = bf16rne(w - bf2f(h));
}

// hi/lo split of a float pair via HW v_cvt_pk_bf16_f32 (~6 VALU / 2 elems).
// __builtin_memcpy (not bit_cast): __hip_bfloat162 isn't trivially copyable
// under hipcc; memcpy folds to a register alias.
#define CVTPAIR(F0, F1, HOUT, LOUT) {                                        \
    __hip_bfloat162 hp_ = __float22bfloat162_rn(make_float2((F0), (F1)));    \
    unsigned hu_; __builtin_memcpy(&hu_, &hp_, 4);                           \
    const float h0_ = __builtin_bit_cast(float, hu_ << 16);                  \
    const float h1_ = __builtin_bit_cast(float, hu_ & 0xffff0000u);          \
    __hip_bfloat162 lp_ = __float22bfloat162_rn(                             \
        make_float2((F0) - h0_, (F1) - h1_));                                \
    unsigned lu_; __builtin_memcpy(&lu_, &lp_, 4);                           \
    HOUT = hu_;                                                              \
    LOUT = lu_;                                                              \
}

// ---- kernel 1: fused split-MFMA logits + in-block reduce + top2 + softmax ----
// Round-4 structure (measured 44us @ 2 waves/SIMD), now 8 waves/block ->
// 4 waves/SIMD. A staged via coalesced 128B global loads -> wave-private LDS
// (no barriers in k-loop); B-frags straight from L2-resident Wh/Wl.
__global__ __launch_bounds__(512, 4)
void moe_fused(const float* __restrict__ x,
               const unsigned short* __restrict__ Wh,
               const unsigned short* __restrict__ Wl,
               float* __restrict__ out, int ntok)
{
    __shared__ __align__(16) char smem[KSPLIT][SLAB];   // 80 KB

    const int t    = threadIdx.x;
    const int w    = t >> 6;            // wave id = k-split id (0..7)
    const int l    = t & 63;
    const int tok0 = blockIdx.x * TOKB;
    const int k0   = w * KRNG;

    unsigned short* stg = (unsigned short*)smem[w];   // wave-private

    const int srow = l >> 3;            // staging row base (0..7)
    const int sg   = l & 7;             // f4 granule within 32-k row
    const int ar   = l & 15;            // a-frag token row within 16-tile
    const int akb  = (l >> 4) * 8;      // frag k-offset (ushorts)
    const int be   = l & 15;            // b-frag expert within 16-tile

    const float* xbase = x + (size_t)tok0 * D + k0 + sg * 4;

    f4 xr0, xr1, xr2, xr3;

    // coalesced: lanes 0..7 cover one row's 32 k (128B); wave = 8 rows/pass
#define LOADX(ch) { \
    const float* p_ = xbase + (ch) * KCH; \
    xr0 = *(const f4*)(p_ + (size_t)(srow     ) * D); \
    xr1 = *(const f4*)(p_ + (size_t)(srow +  8) * D); \
    xr2 = *(const f4*)(p_ + (size_t)(srow + 16) * D); \
    xr3 = *(const f4*)(p_ + (size_t)(srow + 24) * D); }

#define CVT1(v, buf, row) { \
    uint2 hw_, lw_; \
    CVTPAIR(v.x, v.y, hw_.x, lw_.x); \
    CVTPAIR(v.z, v.w, hw_.y, lw_.y); \
    *(uint2*)&stg[(((buf)*2 + 0)*TOKB + (row))*LROW + sg*4] = hw_; \
    *(uint2*)&stg[(((buf)*2 + 1)*TOKB + (row))*LROW + sg*4] = lw_; }

#define CVTWR(buf) { CVT1(xr0, buf, srow); CVT1(xr1, buf, srow+8); \
                     CVT1(xr2, buf, srow+16); CVT1(xr3, buf, srow+24); }

    const f32x4 zz = {0.f, 0.f, 0.f, 0.f};
    f32x4 acc[2][4];
#pragma unroll
    for (int i = 0; i < 2; ++i)
#pragma unroll
        for (int j = 0; j < 4; ++j) acc[i][j] = zz;

    LOADX(0);
    CVTWR(0);

    for (int ch = 0; ch < NCH; ++ch) {
        // B-frags from L2-resident Wh/Wl (lane: expert et*16+be, 8 k at akb)
        bf16x8 bh[4], bl[4];
        const size_t kk = (size_t)(k0 + ch * KCH + akb);
#pragma unroll
        for (int et = 0; et < 4; ++et) {
            const size_t off = (size_t)(et * 16 + be) * D + kk;
            bh[et] = *(const bf16x8*)(Wh + off);
            bl[et] = *(const bf16x8*)(Wl + off);
        }
        // issue next chunk's HBM loads early (T14: issue-early / write-late)
        if (ch + 1 < NCH) LOADX(ch + 1);

        // A-frags from wave-private LDS (pad-40 rows: conflict-light)
        bf16x8 ah[2], al[2];
        const int buf = ch & 1;
#pragma unroll
        for (int rt = 0; rt < 2; ++rt) {
            const int row = rt * 16 + ar;
            ah[rt] = *(const bf16x8*)&stg[((buf*2 + 0)*TOKB + row)*LROW + akb];
            al[rt] = *(const bf16x8*)&stg[((buf*2 + 1)*TOKB + row)*LROW + akb];
        }

        // 3-term split product: xh*wh + xh*wl + xl*wh
#pragma unroll
        for (int rt = 0; rt < 2; ++rt)
#pragma unroll
            for (int et = 0; et < 4; ++et) {
                acc[rt][et] = __builtin_amdgcn_mfma_f32_16x16x32_bf16(ah[rt], bh[et], acc[rt][et], 0, 0, 0);
                acc[rt][et] = __builtin_amdgcn_mfma_f32_16x16x32_bf16(ah[rt], bl[et], acc[rt][et], 0, 0, 0);
                acc[rt][et] = __builtin_amdgcn_mfma_f32_16x16x32_bf16(al[rt], bh[et], acc[rt][et], 0, 0, 0);
            }

        // convert + write next chunk into other buffer (wave-private: no barrier)
        if (ch + 1 < NCH) CVTWR((ch + 1) & 1);
    }

#undef LOADX
#undef CVT1
#undef CVTWR

    // ---- per-wave partials -> LDS (alias dead staging slab) ----
    // C/D layout (verified r4): token = rt*16 + (l>>4)*4 + r, expert = et*16 + (l&15)
    float* cred = (float*)smem[w];                 // [32][68] f32 = 8704 B
#pragma unroll
    for (int rt = 0; rt < 2; ++rt)
#pragma unroll
        for (int et = 0; et < 4; ++et)
#pragma unroll
            for (int r = 0; r < 4; ++r) {
                const int tokl = rt * 16 + (l >> 4) * 4 + r;
                cred[tokl * CSTR + et * 16 + (l & 15)] = acc[rt][et][r];
            }
    __syncthreads();

    // ---- reduce 8 k-splits + top-2 + softmax (256 active threads) ----
    if (t < TOKB * 8) {
        const int tokl = t >> 3;        // 0..31
        const int eg   = t & 7;         // expert octet
        f4 s0 = {0.f,0.f,0.f,0.f}, s1 = {0.f,0.f,0.f,0.f};
#pragma unroll
        for (int ww = 0; ww < KSPLIT; ++ww) {
            const float* cw = (const float*)smem[ww] + tokl * CSTR + eg * 8;
            s0 += *(const f4*)cw;
            s1 += *(const f4*)(cw + 4);
        }
        const float vv[8] = {s0.x, s0.y, s0.z, s0.w, s1.x, s1.y, s1.z, s1.w};
        float m1 = -INFINITY, m2 = -INFINITY;
        int i1 = 0, i2 = 0;
#pragma unroll
        for (int j = 0; j < 8; ++j) {   // ids ascending: strict > = lowest-index tie-break
            const float v = vv[j];
            const int id = eg * 8 + j;
            if (v > m1)      { m2 = m1; i2 = i1; m1 = v; i1 = id; }
            else if (v > m2) { m2 = v;  i2 = id; }
        }
#pragma unroll
        for (int m = 1; m < 8; m <<= 1) {
            const float om1 = __shfl_xor(m1, m);
            const int   oi1 = __shfl_xor(i1, m);
            const float om2 = __shfl_xor(m2, m);
            const int   oi2 = __shfl_xor(i2, m);
            const bool b1 = (om1 > m1) || (om1 == m1 && oi1 < i1);
            const float c2v = b1 ? m1 : om1;  const int c2i = b1 ? i1 : oi1;
            const float c3v = b1 ? om2 : m2;  const int c3i = b1 ? oi2 : i2;
            if (b1) { m1 = om1; i1 = oi1; }
            const bool b2 = (c3v > c2v) || (c3v == c2v && c3i < c2i);
            m2 = b2 ? c3v : c2v;  i2 = b2 ? c3i : c2i;
        }
        if (eg == 0) {
            const int tok = tok0 + tokl;
            out[(size_t)tok * 2 + 0] = (float)i1;
            out[(size_t)tok * 2 + 1] = (float)i2;
            const float p1 = 1.0f / (1.0f + expf(m2 - m1));   // stable: m2 <= m1
            float* vals = out + (size_t)ntok * 2;
            vals[(size_t)tok * 2 + 0] = p1;
            vals[(size_t)tok * 2 + 1] = 1.0f - p1;
        }
    }
}

extern "C" void kernel_launch(void* const* d_in, const int* in_sizes, int n_in,
                              void* d_out, int out_size, void* d_ws, size_t ws_size,
                              hipStream_t stream)
{
    const float* x = (const float*)d_in[0];
    const float* W = (const float*)d_in[1];
    float* out = (float*)d_out;
    unsigned short* Wh = (unsigned short*)d_ws;
    unsigned short* Wl = Wh + (size_t)NE * D;

    const int ntok = in_sizes[0] / D;                 // 16384
    wprep<<<(NE * D) / 256, 256, 0, stream>>>(W, Wh, Wl);
    moe_fused<<<ntok / TOKB, 512, 0, stream>>>(x, Wh, Wl, out, ntok);
}

// Round 8
// 41.680 us; speedup vs baseline: 1.9940x; 1.1631x over previous
//
#include <hip/hip_runtime.h>
#include <hip/hip_bf16.h>
#include <math.h>

typedef float f4 __attribute__((ext_vector_type(4)));
typedef float f32x4 __attribute__((ext_vector_type(4)));
typedef short bf16x8 __attribute__((ext_vector_type(8)));

#define D      2048
#define NE     64
#define TOKB   16               // tokens per block
#define KSPLIT 8                // waves per block, k-split in-block
#define KRNG   (D / KSPLIT)     // 256 k per wave
#define KCH    32               // k per chunk
#define NCH    (KRNG / KCH)     // 8 chunks
#define LROW   40               // ushorts per staged row (16B data pad to 80B)
#define SLAB   5120             // bytes per wave slab: 2buf*2(h/l)*16rows*80B
#define CSTR   68               // f32 stride of reduction rows

__device__ __forceinline__ unsigned short bf16rne(float f) {
    unsigned int u = __builtin_bit_cast(unsigned int, f);
    u += 0x7fffu + ((u >> 16) & 1u);
    return (unsigned short)(u >> 16);
}
__device__ __forceinline__ float bf2f(unsigned short h) {
    unsigned int u = (unsigned int)h << 16;
    return __builtin_bit_cast(float, u);
}

// ---- kernel 0: W -> packed bf16 hi/lo in MFMA B-frag order ----
// Wpk[(kc*4 + et)*512 + l*8 + j] = W[et*16 + (l&15)][kc*32 + (l>>4)*8 + j]
// -> per (chunk,et) a wave loads ONE contiguous 1KB block (lane l: bytes l*16).
__global__ __launch_bounds__(256)
void wprep(const float* __restrict__ W,
           unsigned short* __restrict__ Whp,
           unsigned short* __restrict__ Wlp)
{
    const int i  = blockIdx.x * 256 + threadIdx.x;   // 131072
    const int j  = i & 7;
    const int l  = (i >> 3) & 63;
    const int et = (i >> 9) & 3;
    const int kc = i >> 11;
    const int e  = et * 16 + (l & 15);
    const int k  = kc * 32 + (l >> 4) * 8 + j;
    const float w = W[(size_t)e * D + k];
    const unsigned short h = bf16rne(w);
    Whp[i] = h;
    Wlp[i] = bf16rne(w - bf2f(h));
}

// hi/lo split of a float pair via HW v_cvt_pk_bf16_f32.
// __builtin_memcpy (not bit_cast): __hip_bfloat162 isn't trivially copyable.
#define CVTPAIR(F0, F1, HOUT, LOUT) {                                        \
    __hip_bfloat162 hp_ = __float22bfloat162_rn(make_float2((F0), (F1)));    \
    unsigned hu_; __builtin_memcpy(&hu_, &hp_, 4);                           \
    const float h0_ = __builtin_bit_cast(float, hu_ << 16);                  \
    const float h1_ = __builtin_bit_cast(float, hu_ & 0xffff0000u);          \
    __hip_bfloat162 lp_ = __float22bfloat162_rn(                             \
        make_float2((F0) - h0_, (F1) - h1_));                                \
    unsigned lu_; __builtin_memcpy(&lu_, &lp_, 4);                           \
    HOUT = hu_;                                                              \
    LOUT = lu_;                                                              \
}

// ---- kernel 1: fused split-MFMA logits + in-block reduce + top2 + softmax ----
// r7 skeleton + (a) W packed in frag order (1KB contiguous loads),
// (b) depth-2 x register pipeline (xE/xO parity sets, load->use = 2 chunks).
__global__ __launch_bounds__(512, 4)
void moe_fused(const float* __restrict__ x,
               const unsigned short* __restrict__ Whp,
               const unsigned short* __restrict__ Wlp,
               float* __restrict__ out, int ntok)
{
    __shared__ __align__(16) char smem[KSPLIT][SLAB];   // 40 KB

    const int t    = threadIdx.x;
    const int w    = t >> 6;            // wave id = k-split id (0..7)
    const int l    = t & 63;
    const int tok0 = blockIdx.x * TOKB;
    const int k0   = w * KRNG;

    unsigned short* stg = (unsigned short*)smem[w];   // wave-private

    const int srow = l >> 3;            // staging row (0..7)
    const int sg   = l & 7;             // f4 granule within 32-k row
    const int ar   = l & 15;            // a-frag token row
    const int akb  = (l >> 4) * 8;      // frag k-offset (ushorts)

    const float* xbase = x + (size_t)tok0 * D + k0 + sg * 4;
    // packed W: wave base = (kc=8w, et=0) -> (32w)*512 ushorts
    const unsigned short* whp = Whp + (size_t)w * 16384 + l * 8;
    const unsigned short* wlp = Wlp + (size_t)w * 16384 + l * 8;

    // lanes 0..7 cover one row's 32 k (128B); 2 loads = 16 rows
#define LOADX(ch, R0, R1) { \
    const float* p_ = xbase + (ch) * KCH; \
    R0 = *(const f4*)(p_ + (size_t)(srow    ) * D); \
    R1 = *(const f4*)(p_ + (size_t)(srow + 8) * D); }

#define CVT1(v, buf, row) { \
    uint2 hw_, lw_; \
    CVTPAIR(v.x, v.y, hw_.x, lw_.x); \
    CVTPAIR(v.z, v.w, hw_.y, lw_.y); \
    *(uint2*)&stg[(((buf)*2 + 0)*TOKB + (row))*LROW + sg*4] = hw_; \
    *(uint2*)&stg[(((buf)*2 + 1)*TOKB + (row))*LROW + sg*4] = lw_; }

#define CVTWR(buf, R0, R1) { CVT1(R0, buf, srow); CVT1(R1, buf, srow + 8); }

    // one chunk: 8 contiguous 1KB B-loads, 2 LDS A-frag reads, 12 MFMA
#define CHUNK(ch, buf) { \
    bf16x8 bh[4], bl[4]; \
    _Pragma("unroll") \
    for (int et = 0; et < 4; ++et) { \
        const size_t o_ = (size_t)(4 * (ch) + et) * 512; \
        bh[et] = *(const bf16x8*)(whp + o_); \
        bl[et] = *(const bf16x8*)(wlp + o_); \
    } \
    const bf16x8 ah = *(const bf16x8*)&stg[(((buf)*2 + 0)*TOKB + ar)*LROW + akb]; \
    const bf16x8 al = *(const bf16x8*)&stg[(((buf)*2 + 1)*TOKB + ar)*LROW + akb]; \
    _Pragma("unroll") \
    for (int et = 0; et < 4; ++et) { \
        acc[et] = __builtin_amdgcn_mfma_f32_16x16x32_bf16(ah, bh[et], acc[et], 0, 0, 0); \
        acc[et] = __builtin_amdgcn_mfma_f32_16x16x32_bf16(ah, bl[et], acc[et], 0, 0, 0); \
        acc[et] = __builtin_amdgcn_mfma_f32_16x16x32_bf16(al, bh[et], acc[et], 0, 0, 0); \
    } }

    const f32x4 zz = {0.f, 0.f, 0.f, 0.f};
    f32x4 acc[4] = {zz, zz, zz, zz};

    f4 xE0, xE1, xO0, xO1;                 // depth-2 parity register sets

    // prologue: chunks 0,1,2 in flight / staged
    LOADX(0, xE0, xE1);
    LOADX(1, xO0, xO1);
    CVTWR(0, xE0, xE1);                    // stage chunk 0 -> buf 0
    LOADX(2, xE0, xE1);                    // refill even set

#pragma unroll
    for (int ch = 0; ch < NCH; ch += 2) {
        CHUNK(ch, 0);                      // compute even chunk (buf 0)
        CVTWR(1, xO0, xO1);                // stage ch+1 (loaded 1 iter ago)
        if (ch + 3 < NCH) LOADX(ch + 3, xO0, xO1);
        CHUNK(ch + 1, 1);                  // compute odd chunk (buf 1)
        if (ch + 2 < NCH) CVTWR(0, xE0, xE1);     // stage ch+2
        if (ch + 4 < NCH) LOADX(ch + 4, xE0, xE1);
    }

#undef LOADX
#undef CVT1
#undef CVTWR
#undef CHUNK

    // ---- per-wave partials -> LDS (alias dead staging slab) ----
    // C/D layout (verified r4): token = (l>>4)*4 + r, expert = et*16 + (l&15)
    float* cred = (float*)smem[w];          // [16][68] f32 = 4352 B <= SLAB
#pragma unroll
    for (int et = 0; et < 4; ++et)
#pragma unroll
        for (int r = 0; r < 4; ++r) {
            const int tokl = (l >> 4) * 4 + r;
            cred[tokl * CSTR + et * 16 + (l & 15)] = acc[et][r];
        }
    __syncthreads();

    // ---- reduce 8 k-splits + top-2 + softmax (128 active threads) ----
    if (t < TOKB * 8) {
        const int tokl = t >> 3;        // 0..15
        const int eg   = t & 7;         // expert octet
        f4 s0 = {0.f,0.f,0.f,0.f}, s1 = {0.f,0.f,0.f,0.f};
#pragma unroll
        for (int ww = 0; ww < KSPLIT; ++ww) {
            const float* cw = (const float*)smem[ww] + tokl * CSTR + eg * 8;
            s0 += *(const f4*)cw;
            s1 += *(const f4*)(cw + 4);
        }
        const float vv[8] = {s0.x, s0.y, s0.z, s0.w, s1.x, s1.y, s1.z, s1.w};
        float m1 = -INFINITY, m2 = -INFINITY;
        int i1 = 0, i2 = 0;
#pragma unroll
        for (int j = 0; j < 8; ++j) {   // ids ascending: strict > = lowest-index tie-break
            const float v = vv[j];
            const int id = eg * 8 + j;
            if (v > m1)      { m2 = m1; i2 = i1; m1 = v; i1 = id; }
            else if (v > m2) { m2 = v;  i2 = id; }
        }
#pragma unroll
        for (int m = 1; m < 8; m <<= 1) {
            const float om1 = __shfl_xor(m1, m);
            const int   oi1 = __shfl_xor(i1, m);
            const float om2 = __shfl_xor(m2, m);
            const int   oi2 = __shfl_xor(i2, m);
            const bool b1 = (om1 > m1) || (om1 == m1 && oi1 < i1);
            const float c2v = b1 ? m1 : om1;  const int c2i = b1 ? i1 : oi1;
            const float c3v = b1 ? om2 : m2;  const int c3i = b1 ? oi2 : i2;
            if (b1) { m1 = om1; i1 = oi1; }
            const bool b2 = (c3v > c2v) || (c3v == c2v && c3i < c2i);
            m2 = b2 ? c3v : c2v;  i2 = b2 ? c3i : c2i;
        }
        if (eg == 0) {
            const int tok = tok0 + tokl;
            out[(size_t)tok * 2 + 0] = (float)i1;
            out[(size_t)tok * 2 + 1] = (float)i2;
            const float p1 = 1.0f / (1.0f + expf(m2 - m1));   // stable: m2 <= m1
            float* vals = out + (size_t)ntok * 2;
            vals[(size_t)tok * 2 + 0] = p1;
            vals[(size_t)tok * 2 + 1] = 1.0f - p1;
        }
    }
}

extern "C" void kernel_launch(void* const* d_in, const int* in_sizes, int n_in,
                              void* d_out, int out_size, void* d_ws, size_t ws_size,
                              hipStream_t stream)
{
    const float* x = (const float*)d_in[0];
    const float* W = (const float*)d_in[1];
    float* out = (float*)d_out;
    unsigned short* Whp = (unsigned short*)d_ws;
    unsigned short* Wlp = Whp + (size_t)NE * D;

    const int ntok = in_sizes[0] / D;                 // 16384
    wprep<<<(NE * D) / 256, 256, 0, stream>>>(W, Whp, Wlp);
    moe_fused<<<ntok / TOKB, 512, 0, stream>>>(x, Whp, Wlp, out, ntok);
}

// Round 9
// 39.480 us; speedup vs baseline: 2.1051x; 1.0557x over previous
//
#include <hip/hip_runtime.h>
#include <hip/hip_bf16.h>
#include <math.h>

typedef float f4 __attribute__((ext_vector_type(4)));
typedef float f32x4 __attribute__((ext_vector_type(4)));
typedef short bf16x8 __attribute__((ext_vector_type(8)));

#define D      2048
#define NE     64
#define TOKB   32               // tokens per block (2 token-groups of 16)
#define NKG    4                // k-groups (waves per token-group)
#define KRNG   (D / NKG)        // 512 k per wave
#define KCH    32               // k per chunk
#define NCH    (KRNG / KCH)     // 16 chunks per wave
#define LROW   40               // ushorts per staged row (64B data + 16B pad)
#define SLAB   5120             // bytes per wave slab: 2buf*2(h/l)*16rows*80B
#define CSTR   68               // f32 stride of reduction rows

__device__ __forceinline__ unsigned short bf16rne(float f) {
    unsigned int u = __builtin_bit_cast(unsigned int, f);
    u += 0x7fffu + ((u >> 16) & 1u);
    return (unsigned short)(u >> 16);
}
__device__ __forceinline__ float bf2f(unsigned short h) {
    unsigned int u = (unsigned int)h << 16;
    return __builtin_bit_cast(float, u);
}

// ---- kernel 0: W -> packed bf16 hi/lo in MFMA B-frag order ----
// Wpk[(kc*4 + et)*512 + l*8 + j] = W[et*16 + (l&15)][kc*32 + (l>>4)*8 + j]
// -> per (chunk,et) a wave loads ONE contiguous 1KB block (lane l: bytes l*16).
__global__ __launch_bounds__(256)
void wprep(const float* __restrict__ W,
           unsigned short* __restrict__ Whp,
           unsigned short* __restrict__ Wlp)
{
    const int i  = blockIdx.x * 256 + threadIdx.x;   // 131072
    const int j  = i & 7;
    const int l  = (i >> 3) & 63;
    const int et = (i >> 9) & 3;
    const int kc = i >> 11;
    const int e  = et * 16 + (l & 15);
    const int k  = kc * 32 + (l >> 4) * 8 + j;
    const float w = W[(size_t)e * D + k];
    const unsigned short h = bf16rne(w);
    Whp[i] = h;
    Wlp[i] = bf16rne(w - bf2f(h));
}

// hi/lo split of a float pair via HW v_cvt_pk_bf16_f32.
// __builtin_memcpy (not bit_cast): __hip_bfloat162 isn't trivially copyable.
#define CVTPAIR(F0, F1, HOUT, LOUT) {                                        \
    __hip_bfloat162 hp_ = __float22bfloat162_rn(make_float2((F0), (F1)));    \
    unsigned hu_; __builtin_memcpy(&hu_, &hp_, 4);                           \
    const float h0_ = __builtin_bit_cast(float, hu_ << 16);                  \
    const float h1_ = __builtin_bit_cast(float, hu_ & 0xffff0000u);          \
    __hip_bfloat162 lp_ = __float22bfloat162_rn(                             \
        make_float2((F0) - h0_, (F1) - h1_));                                \
    unsigned lu_; __builtin_memcpy(&lu_, &lp_, 4);                           \
    HOUT = hu_;                                                              \
    LOUT = lu_;                                                              \
}

// ---- kernel 1: fused split-MFMA logits + in-block reduce + top2 + softmax ----
// 8 waves = 2 token-groups (tg) x 4 k-groups (kg). Each wave: one 16-token
// tile over K/4. W L2 traffic halved vs r8 (268 MB total); tg-pair waves
// share W addresses (L1 hit). r8's proven staging/pipeline skeleton kept.
__global__ __launch_bounds__(512, 4)
void moe_fused(const float* __restrict__ x,
               const unsigned short* __restrict__ Whp,
               const unsigned short* __restrict__ Wlp,
               float* __restrict__ out, int ntok)
{
    __shared__ __align__(16) char smem[8][SLAB];   // 40 KB

    const int t    = threadIdx.x;
    const int w    = t >> 6;            // wave id
    const int l    = t & 63;
    const int tg   = w >> 2;            // token-group (0..1)
    const int kg   = w & 3;             // k-group (0..3)
    const int tok0 = blockIdx.x * TOKB;

    unsigned short* stg = (unsigned short*)smem[w];   // wave-private

    const int srow = l >> 3;            // staging row (0..7)
    const int sg   = l & 7;             // f4 granule within 32-k row
    const int ar   = l & 15;            // a-frag token row
    const int akb  = (l >> 4) * 8;      // frag k-offset (ushorts)

    const float* xbase = x + (size_t)(tok0 + tg * 16) * D + kg * KRNG + sg * 4;
    // packed W: k-group base = kc = kg*16 -> (kg*16*4)*512 ushorts
    const unsigned short* whp = Whp + (size_t)kg * 32768 + l * 8;
    const unsigned short* wlp = Wlp + (size_t)kg * 32768 + l * 8;

    // lanes 0..7 cover one row's 32 k (128B); 2 loads = 16 rows
#define LOADX(ch, R0, R1) { \
    const float* p_ = xbase + (ch) * KCH; \
    R0 = *(const f4*)(p_ + (size_t)(srow    ) * D); \
    R1 = *(const f4*)(p_ + (size_t)(srow + 8) * D); }

#define CVT1(v, buf, row) { \
    uint2 hw_, lw_; \
    CVTPAIR(v.x, v.y, hw_.x, lw_.x); \
    CVTPAIR(v.z, v.w, hw_.y, lw_.y); \
    *(uint2*)&stg[(((buf)*2 + 0)*16 + (row))*LROW + sg*4] = hw_; \
    *(uint2*)&stg[(((buf)*2 + 1)*16 + (row))*LROW + sg*4] = lw_; }

#define CVTWR(buf, R0, R1) { CVT1(R0, buf, srow); CVT1(R1, buf, srow + 8); }

    // one chunk: 8 contiguous 1KB B-loads, 2 LDS A-frag reads, 12 MFMA
#define CHUNK(ch, buf) { \
    bf16x8 bh[4], bl[4]; \
    _Pragma("unroll") \
    for (int et = 0; et < 4; ++et) { \
        const size_t o_ = (size_t)(4 * (ch) + et) * 512; \
        bh[et] = *(const bf16x8*)(whp + o_); \
        bl[et] = *(const bf16x8*)(wlp + o_); \
    } \
    const bf16x8 ah = *(const bf16x8*)&stg[(((buf)*2 + 0)*16 + ar)*LROW + akb]; \
    const bf16x8 al = *(const bf16x8*)&stg[(((buf)*2 + 1)*16 + ar)*LROW + akb]; \
    _Pragma("unroll") \
    for (int et = 0; et < 4; ++et) { \
        acc[et] = __builtin_amdgcn_mfma_f32_16x16x32_bf16(ah, bh[et], acc[et], 0, 0, 0); \
        acc[et] = __builtin_amdgcn_mfma_f32_16x16x32_bf16(ah, bl[et], acc[et], 0, 0, 0); \
        acc[et] = __builtin_amdgcn_mfma_f32_16x16x32_bf16(al, bh[et], acc[et], 0, 0, 0); \
    } }

    const f32x4 zz = {0.f, 0.f, 0.f, 0.f};
    f32x4 acc[4] = {zz, zz, zz, zz};

    f4 xE0, xE1, xO0, xO1;                 // depth-2 parity register sets

    // prologue: chunks 0,1,2 in flight / staged
    LOADX(0, xE0, xE1);
    LOADX(1, xO0, xO1);
    CVTWR(0, xE0, xE1);                    // stage chunk 0 -> buf 0
    LOADX(2, xE0, xE1);                    // refill even set

#pragma unroll
    for (int ch = 0; ch < NCH; ch += 2) {
        CHUNK(ch, 0);                      // compute even chunk (buf 0)
        CVTWR(1, xO0, xO1);                // stage ch+1 (loaded 1 iter ago)
        if (ch + 3 < NCH) LOADX(ch + 3, xO0, xO1);
        CHUNK(ch + 1, 1);                  // compute odd chunk (buf 1)
        if (ch + 2 < NCH) CVTWR(0, xE0, xE1);     // stage ch+2
        if (ch + 4 < NCH) LOADX(ch + 4, xE0, xE1);
    }

#undef LOADX
#undef CVT1
#undef CVTWR
#undef CHUNK

    // ---- per-wave partials -> LDS (alias dead staging slab) ----
    // C/D layout (verified r4): token = (l>>4)*4 + r, expert = et*16 + (l&15)
    float* cred = (float*)smem[w];          // [16][68] f32 = 4352 B <= SLAB
#pragma unroll
    for (int et = 0; et < 4; ++et)
#pragma unroll
        for (int r = 0; r < 4; ++r) {
            const int tokl = (l >> 4) * 4 + r;
            cred[tokl * CSTR + et * 16 + (l & 15)] = acc[et][r];
        }
    __syncthreads();

    // ---- reduce 4 k-groups + top-2 + softmax (256 active threads) ----
    if (t < TOKB * 8) {
        const int tokl = t >> 3;        // 0..31 (block-local token)
        const int eg   = t & 7;         // expert octet
        const int tgr  = tokl >> 4;     // token-group of this token
        const int row  = tokl & 15;     // row within the group's tile
        f4 s0 = {0.f,0.f,0.f,0.f}, s1 = {0.f,0.f,0.f,0.f};
#pragma unroll
        for (int kk = 0; kk < NKG; ++kk) {
            const float* cw = (const float*)smem[tgr * 4 + kk] + row * CSTR + eg * 8;
            s0 += *(const f4*)cw;
            s1 += *(const f4*)(cw + 4);
        }
        const float vv[8] = {s0.x, s0.y, s0.z, s0.w, s1.x, s1.y, s1.z, s1.w};
        float m1 = -INFINITY, m2 = -INFINITY;
        int i1 = 0, i2 = 0;
#pragma unroll
        for (int j = 0; j < 8; ++j) {   // ids ascending: strict > = lowest-index tie-break
            const float v = vv[j];
            const int id = eg * 8 + j;
            if (v > m1)      { m2 = m1; i2 = i1; m1 = v; i1 = id; }
            else if (v > m2) { m2 = v;  i2 = id; }
        }
#pragma unroll
        for (int m = 1; m < 8; m <<= 1) {
            const float om1 = __shfl_xor(m1, m);
            const int   oi1 = __shfl_xor(i1, m);
            const float om2 = __shfl_xor(m2, m);
            const int   oi2 = __shfl_xor(i2, m);
            const bool b1 = (om1 > m1) || (om1 == m1 && oi1 < i1);
            const float c2v = b1 ? m1 : om1;  const int c2i = b1 ? i1 : oi1;
            const float c3v = b1 ? om2 : m2;  const int c3i = b1 ? oi2 : i2;
            if (b1) { m1 = om1; i1 = oi1; }
            const bool b2 = (c3v > c2v) || (c3v == c2v && c3i < c2i);
            m2 = b2 ? c3v : c2v;  i2 = b2 ? c3i : c2i;
        }
        if (eg == 0) {
            const int tok = tok0 + tokl;
            out[(size_t)tok * 2 + 0] = (float)i1;
            out[(size_t)tok * 2 + 1] = (float)i2;
            const float p1 = 1.0f / (1.0f + expf(m2 - m1));   // stable: m2 <= m1
            float* vals = out + (size_t)ntok * 2;
            vals[(size_t)tok * 2 + 0] = p1;
            vals[(size_t)tok * 2 + 1] = 1.0f - p1;
        }
    }
}

extern "C" void kernel_launch(void* const* d_in, const int* in_sizes, int n_in,
                              void* d_out, int out_size, void* d_ws, size_t ws_size,
                              hipStream_t stream)
{
    const float* x = (const float*)d_in[0];
    const float* W = (const float*)d_in[1];
    float* out = (float*)d_out;
    unsigned short* Whp = (unsigned short*)d_ws;
    unsigned short* Wlp = Whp + (size_t)NE * D;

    const int ntok = in_sizes[0] / D;                 // 16384
    wprep<<<(NE * D) / 256, 256, 0, stream>>>(W, Whp, Wlp);
    moe_fused<<<ntok / TOKB, 512, 0, stream>>>(x, Whp, Wlp, out, ntok);
}